// Round 14
// baseline (319.225 us; speedup 1.0000x reference)
//
#include <hip/hip_runtime.h>
#include <hip/hip_fp16.h>
#include <stdint.h>

// ---------------------------------------------------------------------------
// GroupAttentionLayer: RF=16,STRIDE=16 windows tile the image exactly =>
//   yout = leaky(Q K^T / 16) V  (full dense attention per batch), then BN +
//   spatial softmax (mu/beta cancel; only a_c = g1/sqrt(var+eps) survives).
// B=4, P=4096 px/batch (T=16384 rows), C=256. Inputs fp32, OUTPUT fp32.
// R7:  k_attn operands FRAGMENT-MAJOR in global (lane-contiguous 1KB loads).
// R8:  BN stats fused into GEMM epilogue; frag-major YQK; setprio (+7%).
// R9:  launch fusion (7 kernels); coefs inline in k_bn; 1/16 into Q coefs.
// R10: q-tile 128 -> SLOWER (latency-bound at 1 blk/CU). REVERTED.
// R11: Gram-matrix analytic stats -> REGRESSION. REVERTED.
// R12: split-K fusion w/ __threadfence -> CATASTROPHIC (L2 flush). REVERTED.
// R13: cooperative grid.sync tail -> 105us for 50MB. REVERTED.
// R14: float4 tail + gemm grid swap -> 242.7us.
// R15: bf16 Y + XCD-pinned gemm + vectorized k_bn V -> 240.95us.
// R16: m97-structure QKV GEMM -> 230.0us; absmax 1.22e-4.
// R17: attn V-prefetch -> spill REGRESSION. REVERTED.
// R18: soft 1024-blk -> noise. Reverted.
// R19: swapped-QK^T S-convert (cvt_pk+permlane) -> time-null. Kept.
// R20: FP16 tail intermediates -> 226.1us (BEST); absmax 1.83e-4; attn
//      WRITE 32768->16384KB (attn dur unchanged -> not write-bound).
// R21 (this round): SINGLE-BARRIER attn iteration. Sl double-buffered
//      (2x33.8KB); Ql dropped (Q frags read from global, L2-hot, identical
//      indexing); barriers/iter 2 -> 1 (16 -> 8 per block). Hazard proof:
//      bar(kt-1) separates ph2(kt-2) reads of buf[kt&1] from ph1(kt) writes
//      (wave passes bar(kt-1) only after ph2(kt-2)); bar(kt) separates
//      ph1(kt) writes from ph2(kt) reads; ph1(kt+1) writes buf[(kt+1)&1]
//      != buf read by ph2(kt). Watch: FETCH (L2 thrash), WRITE (spill).
//   Qf/Kf[((g*16+ks)*64+lane)*8+j] : row=g*32+(lane&31), ch=ks*16+(lane>>5)*8+j
//   Vf[((gc*256+kp)*64+lane)*8+j]  : ch=(gc&7)*32+(lane&31), key=kp*16+(lane>>5)*8+j
// ---------------------------------------------------------------------------

typedef __attribute__((ext_vector_type(8)))  short short8;   // 8 x bf16
typedef __attribute__((ext_vector_type(4)))  float f32x4;    // 16x16 acc
typedef __attribute__((ext_vector_type(16))) float f32x16;   // 32x32 acc
typedef __attribute__((ext_vector_type(4)))  unsigned short ushort4v;

#define ALPHA 0.3f
#define EPS   1e-3
#define NTOT  16384.0

#define GLOAD_LDS16(gp, lp) __builtin_amdgcn_global_load_lds( \
    (const __attribute__((address_space(1))) void*)(gp), \
    (__attribute__((address_space(3))) void*)(lp), 16, 0, 0)

__device__ __forceinline__ unsigned short f2bf(float f){
  unsigned u = __float_as_uint(f);
  u += 0x7FFFu + ((u>>16)&1u);          // RNE
  return (unsigned short)(u>>16);
}
__device__ __forceinline__ float bf2f(unsigned short u){
  return __uint_as_float((unsigned)u << 16);
}
__device__ __forceinline__ float lrelu(float x){ return fmaxf(x, ALPHA*x); }
__device__ __forceinline__ float h2f(unsigned short u){
  return __half2float(__ushort_as_half(u));
}
__device__ __forceinline__ unsigned short f2h(float f){
  return __half_as_ushort(__float2half(f));
}

// ------------------------------------------------- prep: cvt + wtrans + zero
__global__ __launch_bounds__(256)
void k_prep(const float* __restrict__ X,
            const float* __restrict__ Wq,
            const float* __restrict__ Wk,
            const float* __restrict__ Wv,
            unsigned short* __restrict__ Xb,
            unsigned short* __restrict__ Wt,
            float* __restrict__ zws){
  int blk = blockIdx.x, tid = threadIdx.x;
  if (blk < 4096){
    int i = (blk*256 + tid)*4;
    float4 v = *(const float4*)(X + i);
    ushort4v o; o.x = f2bf(v.x); o.y = f2bf(v.y); o.z = f2bf(v.z); o.w = f2bf(v.w);
    *(ushort4v*)(Xb + i) = o;
  } else {
    int o = (blk - 4096)*256 + tid;              // 0 .. 196607
    int p = o >> 16, rem = o & 65535;
    int j = rem >> 8, c = rem & 255;
    const float* W = (p==0) ? Wq : ((p==1) ? Wk : Wv);
    Wt[o] = f2bf(W[c*256 + j]);
    if (o < 5120) zws[o] = 0.f;                  // st + sums
  }
}

// --------------------------------------------------------------- QKV GEMM
// m97 structure: 128x128 tile, BK=64, 768 blocks (xcd-pinned), 4 waves.
// A/B staged via global_load_lds dwordx4 into linear [128][64] LDS.
// Q/K planes (nb<4) -> frag-major BF16 YQK; V (nb>=4) -> row-major BF16 Yv.
// BN stats (fp32 partials -> LDS -> f64 atomics) in the epilogue.
__global__ __launch_bounds__(256)
void k_qkv_gemm(const unsigned short* __restrict__ X,
                const unsigned short* __restrict__ Wt,
                unsigned short* __restrict__ YQK, unsigned short* __restrict__ Yv,
                double* __restrict__ st){
  __shared__ __align__(16) unsigned short At[128*64];   // 16KB
  __shared__ __align__(16) unsigned short Bt[128*64];   // 16KB
  int tid = threadIdx.x;
  int g = blockIdx.x;
  int xcd = g & 7, r8 = g >> 3;          // 96 per XCD = 16 mb x 6 nb
  int mb = xcd*16 + r8/6, nb = r8 % 6;
  int lane = tid & 63, w = tid >> 6;
  int ln15 = lane & 15, quad = lane >> 4;
  int rw = (w & 1)*64, cw = (w >> 1)*64;       // 2x2 waves, 64x64 each

  const unsigned short* gaL = X  + ((size_t)(mb*128 + (lane>>3)))*256 + (lane&7)*8;
  const unsigned short* gbL = Wt + ((size_t)(nb*128 + (lane>>3)))*256 + (lane&7)*8;

  f32x4 acc[4][4] = {};
  for (int kt = 0; kt < 4; ++kt){
    const unsigned short* ga = gaL + kt*64;
    const unsigned short* gb = gbL + kt*64;
#pragma unroll
    for (int j = 0; j < 4; ++j){
      int s = w*4 + j;                         // segment 0..15
      GLOAD_LDS16(ga + (size_t)s*8*256, At + s*512);
      GLOAD_LDS16(gb + (size_t)s*8*256, Bt + s*512);
    }
    __syncthreads();
#pragma unroll
    for (int ksub = 0; ksub < 2; ++ksub){
      short8 af[4], bf[4];
#pragma unroll
      for (int mt = 0; mt < 4; ++mt)
        af[mt] = *(const short8*)(At + (rw + mt*16 + ln15)*64 + ksub*32 + quad*8);
#pragma unroll
      for (int nt = 0; nt < 4; ++nt)
        bf[nt] = *(const short8*)(Bt + (cw + nt*16 + ln15)*64 + ksub*32 + quad*8);
#pragma unroll
      for (int mt = 0; mt < 4; ++mt)
#pragma unroll
        for (int nt = 0; nt < 4; ++nt)
          acc[mt][nt] = __builtin_amdgcn_mfma_f32_16x16x32_bf16(af[mt], bf[nt], acc[mt][nt], 0,0,0);
    }
    __syncthreads();
  }
  // ---- per-lane column partials for BN stats (raw fp32 Y values)
  float ps[4] = {0,0,0,0}, pq[4] = {0,0,0,0};
#pragma unroll
  for (int mt = 0; mt < 4; ++mt)
#pragma unroll
    for (int nt = 0; nt < 4; ++nt)
#pragma unroll
      for (int rr = 0; rr < 4; ++rr){
        float v = acc[mt][nt][rr];
        ps[nt] += v; pq[nt] += v*v;
      }
  // ---- C-store (bf16)
  if (nb < 4){
    int proj = nb >> 1;                        // 0=Q (nb 0,1), 1=K (nb 2,3)
    unsigned short* base = YQK + (size_t)proj*(16384*256);
#pragma unroll
    for (int nt = 0; nt < 4; ++nt){
      int ch_g = (nb&1)*128 + cw + nt*16 + ln15;
      int ksf = ch_g >> 4, l5c = (ch_g >> 3) & 1, j = ch_g & 7;
#pragma unroll
      for (int mt = 0; mt < 4; ++mt){
        int row0 = mb*128 + rw + mt*16 + quad*4;
        int gg = row0 >> 5, l31r0 = row0 & 31;
#pragma unroll
        for (int rr = 0; rr < 4; ++rr){
          size_t chunk = (size_t)((gg*16 + ksf)*64 + l5c*32 + l31r0 + rr);
          base[chunk*8 + j] = f2bf(acc[mt][nt][rr]);
        }
      }
    }
  } else {
    int vc0 = (nb - 4)*128 + cw;
#pragma unroll
    for (int mt = 0; mt < 4; ++mt)
#pragma unroll
      for (int nt = 0; nt < 4; ++nt)
#pragma unroll
        for (int rr = 0; rr < 4; ++rr){
          int row = mb*128 + rw + mt*16 + quad*4 + rr;
          Yv[(size_t)row*256 + vc0 + nt*16 + ln15] = f2bf(acc[mt][nt][rr]);
        }
  }
  // ---- stats reduce: LDS (reuse At, 256 f32) then f64 atomics per channel
  __syncthreads();
  float* red = (float*)At;                     // [0..128) sum, [128..256) sq
  red[tid] = 0.f;
  __syncthreads();
#pragma unroll
  for (int nt = 0; nt < 4; ++nt){
    int colL = cw + nt*16 + ln15;              // 0..127
    atomicAdd(&red[colL],       ps[nt]);
    atomicAdd(&red[128 + colL], pq[nt]);
  }
  __syncthreads();
  if (tid < 128){
    int cc = nb*128 + tid;                     // global channel 0..767
    atomicAdd(&st[cc],       (double)red[tid]);
    atomicAdd(&st[768 + cc], (double)red[128 + tid]);
  }
}

// ------------------------------------------------- BN+leaky: Q,K frag stream
// + V transpose, one dispatch. Coefs computed inline from st. Y is BF16.
// Q coefs carry an extra 1/16 (score scale folded in; exact exponent shift).
__global__ __launch_bounds__(256)
void k_bn(const unsigned short* __restrict__ YQK, const unsigned short* __restrict__ Yv,
          const double* __restrict__ st,
          const float* __restrict__ gq, const float* __restrict__ bq,
          const float* __restrict__ gk, const float* __restrict__ bk,
          const float* __restrict__ gv, const float* __restrict__ bv,
          unsigned short* __restrict__ Qf, unsigned short* __restrict__ Kf,
          unsigned short* __restrict__ Vf){
  __shared__ float sc_s[256], sh_s[256];
  __shared__ unsigned short tile[64][66];
  int tid = threadIdx.x;
  int blk = blockIdx.x;
  if (blk < 4096){
    int proj = blk >> 11;                        // 2048 blocks per proj (0=Q,1=K)
    {
      int c = tid;
      int cc = proj*256 + c;
      double mu  = st[cc]     * (1.0/NTOT);
      double var = st[768+cc] * (1.0/NTOT) - mu*mu;
      double g = proj ? (double)gk[c] : (double)gq[c];
      double b = proj ? (double)bk[c] : (double)bq[c];
      double a = g / sqrt(var + EPS);
      float f = proj ? 1.f : 0.0625f;            // fold 1/16 into Q
      sc_s[c] = (float)a * f;
      sh_s[c] = (float)(b - mu*a) * f;
    }
    __syncthreads();
    int oc = blk*256 + tid;                      // chunk of 8 bf16 values
    int rest = oc & 524287;
    int ks = (rest >> 6) & 15, l5c = (rest >> 5) & 1;
    int ch0 = ks*16 + l5c*8;
    uint4 yin = *(const uint4*)(YQK + (size_t)oc*8);
    const unsigned short* yp = (const unsigned short*)&yin;
    const float* sc = sc_s + ch0;
    const float* sh = sh_s + ch0;
    unsigned short rr[8];
#pragma unroll
    for (int e = 0; e < 8; ++e){
      float v = bf2f(yp[e]);
      rr[e] = f2bf(lrelu(v*sc[e] + sh[e]));
    }
    uint4 u;
    u.x = (unsigned)rr[0] | ((unsigned)rr[1]<<16);
    u.y = (unsigned)rr[2] | ((unsigned)rr[3]<<16);
    u.z = (unsigned)rr[4] | ((unsigned)rr[5]<<16);
    u.w = (unsigned)rr[6] | ((unsigned)rr[7]<<16);
    *(uint4*)((proj ? Kf : Qf) + (size_t)rest*8) = u;
  } else {
    int b2 = blk - 4096;
    int pt = b2 & 63, ct = (b2 >> 6) & 3, b = b2 >> 8;
    if (tid < 64){
      int c = ct*64 + tid;
      int cc = 512 + c;
      double mu  = st[cc]     * (1.0/NTOT);
      double var = st[768+cc] * (1.0/NTOT) - mu*mu;
      double a = (double)gv[c] / sqrt(var + EPS);
      sc_s[tid] = (float)a;
      sh_s[tid] = (float)((double)bv[c] - mu*a);
    }
    __syncthreads();
#pragma unroll
    for (int kpass = 0; kpass < 2; ++kpass){
      int idx = kpass*256 + tid;                 // 0..511
      int px = idx >> 3, co = idx & 7;
      size_t t = (size_t)b*4096 + pt*64 + px;
      uint4 u = *(const uint4*)(Yv + t*256 + ct*64 + co*8);
      const unsigned short* up = (const unsigned short*)&u;
      int c0 = co*8;
#pragma unroll
      for (int e = 0; e < 8; ++e){
        float v = bf2f(up[e]);
        tile[px][c0+e] = f2bf(lrelu(v*sc_s[c0+e] + sh_s[c0+e]));
      }
    }
    __syncthreads();
#pragma unroll
    for (int it = 0; it < 2; ++it){
      int m = it*256 + tid;                      // 512 chunks of 8 keys
      int c2 = m >> 3, kg = m & 7;
      int ch = ct*64 + c2;
      int gc = b*8 + (ch >> 5), l31c = ch & 31;
      int kp = pt*4 + (kg >> 1), l5k = kg & 1;
      unsigned short r0 = tile[kg*8+0][c2], r1 = tile[kg*8+1][c2];
      unsigned short r2 = tile[kg*8+2][c2], r3 = tile[kg*8+3][c2];
      unsigned short r4 = tile[kg*8+4][c2], r5 = tile[kg*8+5][c2];
      unsigned short r6 = tile[kg*8+6][c2], r7 = tile[kg*8+7][c2];
      uint4 u;
      u.x = (unsigned)r0 | ((unsigned)r1<<16);
      u.y = (unsigned)r2 | ((unsigned)r3<<16);
      u.z = (unsigned)r4 | ((unsigned)r5<<16);
      u.w = (unsigned)r6 | ((unsigned)r7<<16);
      *(uint4*)(Vf + ((size_t)((gc*256 + kp)*64 + l5k*32 + l31c))*8) = u;
    }
  }
}

// --------------------------------------------------------------- attention
// R21: single-barrier iteration. 512 blocks x 512 threads, q-tile 64.
// blk&7 = (b,half) -> XCD-pinned. Sl double-buffered (2x33.8KB); Q frags
// read from global (L2-hot, same indexing Ql had). 8 iters of BK=256,
// ONE barrier/iter. setprio(1) wraps MFMA phases. Swapped-QK^T S-convert
// (cvt_pk+permlane). P stored fp16.
__global__ __launch_bounds__(512, 4)
void k_attn(const unsigned short* __restrict__ Qf,
            const unsigned short* __restrict__ Kf,
            const unsigned short* __restrict__ Vf,
            __half* __restrict__ P0, __half* __restrict__ P1){
  __shared__ __align__(16) unsigned short Sl[2][64*264];  // double-buffered S
  int tid = threadIdx.x;
  int blk = blockIdx.x;
  int qt = blk >> 3, combo = blk & 7;
  int b = combo >> 1, half = combo & 1;
  int q0 = qt*64;
  int lane = tid & 63, w = tid >> 6;
  int l31 = lane & 31, l5 = lane >> 5;
  __half* P = half ? P1 : P0;

  int gq0 = b*128 + qt*2;
  const unsigned short* qa0 = Qf + (size_t)gq0*8192 + lane*8;       // + ks*512
  const unsigned short* qa1 = Qf + (size_t)(gq0+1)*8192 + lane*8;

  f32x16 acc2[2] = {};
  int gk0 = b*128 + half*64 + w;
  const unsigned short* kb = Kf + (size_t)gk0*8192 + lane*8;
  const unsigned short* vb = Vf + ((size_t)((b*8 + w)*256 + half*128))*512 + lane*8;

  for (int kt = 0; kt < 8; ++kt){
    unsigned short* slb = &Sl[kt & 1][0];
    f32x16 a1[2] = {};
    const unsigned short* kbt = kb + (size_t)kt*8*8192;
    __builtin_amdgcn_s_setprio(1);
#pragma unroll
    for (int ks = 0; ks < 16; ++ks){
      short8 kf  = *(const short8*)(kbt + ks*512);
      short8 q0v = *(const short8*)(qa0 + ks*512);
      short8 q1v = *(const short8*)(qa1 + ks*512);
      a1[0] = __builtin_amdgcn_mfma_f32_32x32x16_bf16(kf, q0v, a1[0], 0, 0, 0);
      a1[1] = __builtin_amdgcn_mfma_f32_32x32x16_bf16(kf, q1v, a1[1], 0, 0, 0);
    }
    __builtin_amdgcn_s_setprio(0);
    // S-convert straight into buf[kt&1]: no barrier needed before the write
    // (readers of this buffer finished before bar(kt-1); see header proof).
#pragma unroll
    for (int c = 0; c < 2; ++c){
      float t[16];
#pragma unroll
      for (int r = 0; r < 16; ++r){
        float x = a1[c][r];
        t[r] = fmaxf(x, 0.3f*x);
      }
      unsigned p0,p1,p2,p3,p4,p5,p6,p7;
      asm("v_cvt_pk_bf16_f32 %0, %1, %2" : "=v"(p0) : "v"(t[0]),  "v"(t[1]));
      asm("v_cvt_pk_bf16_f32 %0, %1, %2" : "=v"(p1) : "v"(t[2]),  "v"(t[3]));
      asm("v_cvt_pk_bf16_f32 %0, %1, %2" : "=v"(p2) : "v"(t[4]),  "v"(t[5]));
      asm("v_cvt_pk_bf16_f32 %0, %1, %2" : "=v"(p3) : "v"(t[6]),  "v"(t[7]));
      asm("v_cvt_pk_bf16_f32 %0, %1, %2" : "=v"(p4) : "v"(t[8]),  "v"(t[9]));
      asm("v_cvt_pk_bf16_f32 %0, %1, %2" : "=v"(p5) : "v"(t[10]), "v"(t[11]));
      asm("v_cvt_pk_bf16_f32 %0, %1, %2" : "=v"(p6) : "v"(t[12]), "v"(t[13]));
      asm("v_cvt_pk_bf16_f32 %0, %1, %2" : "=v"(p7) : "v"(t[14]), "v"(t[15]));
      asm volatile("v_permlane32_swap_b32 %0, %1" : "+v"(p0), "+v"(p4));
      asm volatile("v_permlane32_swap_b32 %0, %1" : "+v"(p1), "+v"(p5));
      asm volatile("v_permlane32_swap_b32 %0, %1" : "+v"(p2), "+v"(p6));
      asm volatile("v_permlane32_swap_b32 %0, %1" : "+v"(p3), "+v"(p7));
      uint4 u0; u0.x = p0; u0.y = p1; u0.z = p4; u0.w = p5;   // keys +0..7
      uint4 u1; u1.x = p2; u1.y = p3; u1.z = p6; u1.w = p7;   // keys +8..15
      unsigned short* dstp = slb + (c*32 + l31)*264 + w*32 + l5*16;
      *(uint4*)(dstp)     = u0;
      *(uint4*)(dstp + 8) = u1;
    }
    __syncthreads();     // the single barrier: S visible for phase 2
    const unsigned short* vbt = vb + (size_t)kt*16*512;
    __builtin_amdgcn_s_setprio(1);
#pragma unroll
    for (int kk = 0; kk < 16; ++kk){
      short8 vf = *(const short8*)(vbt + kk*512);
      short8 s0 = *(const short8*)(slb + (     l31)*264 + kk*16 + l5*8);
      short8 s1 = *(const short8*)(slb + (32 + l31)*264 + kk*16 + l5*8);
      acc2[0] = __builtin_amdgcn_mfma_f32_32x32x16_bf16(s0, vf, acc2[0], 0, 0, 0);
      acc2[1] = __builtin_amdgcn_mfma_f32_32x32x16_bf16(s1, vf, acc2[1], 0, 0, 0);
    }
    __builtin_amdgcn_s_setprio(0);
  }
#pragma unroll
  for (int c = 0; c < 2; ++c)
#pragma unroll
    for (int reg = 0; reg < 16; ++reg){
      int row = q0 + c*32 + (reg & 3) + 8*(reg >> 2) + 4*l5;
      P[((size_t)b*4096 + row)*256 + w*32 + l31] = __float2half(acc2[c][reg]);
    }
}

// ------------------------------------------------- partial reduce + BN stats
// 512 blocks x 32 rows. FP16 in/out: thread owns 8 consecutive channels
// (16B/lane); f32 partials -> LDS -> f64 atomics (same accumulation class).
__global__ __launch_bounds__(256)
void k_red(const __half* __restrict__ P0, const __half* __restrict__ P1,
           __half* __restrict__ yout, double* __restrict__ st){
  __shared__ float redS[8][256];
  __shared__ float redQ[8][256];
  int tid = threadIdx.x;
  int cg = (tid & 31)*8, pg = tid >> 5;        // 32 ch-groups x 8 px-groups
  int r0 = blockIdx.x*32;
  float s[8] = {0,0,0,0,0,0,0,0}, q[8] = {0,0,0,0,0,0,0,0};
#pragma unroll
  for (int k = 0; k < 4; ++k){
    size_t idx = (size_t)(r0 + pg + k*8)*256 + cg;
    uint4 ua = *(const uint4*)(P0 + idx);
    uint4 ub = *(const uint4*)(P1 + idx);
    const unsigned short* pa = (const unsigned short*)&ua;
    const unsigned short* pb = (const unsigned short*)&ub;
    unsigned short ho[8];
#pragma unroll
    for (int e = 0; e < 8; ++e){
      float v = h2f(pa[e]) + h2f(pb[e]);
      ho[e] = f2h(v);
      s[e] += v; q[e] += v*v;
    }
    uint4 uo;
    uo.x = (unsigned)ho[0] | ((unsigned)ho[1]<<16);
    uo.y = (unsigned)ho[2] | ((unsigned)ho[3]<<16);
    uo.z = (unsigned)ho[4] | ((unsigned)ho[5]<<16);
    uo.w = (unsigned)ho[6] | ((unsigned)ho[7]<<16);
    *(uint4*)(yout + idx) = uo;
  }
#pragma unroll
  for (int e = 0; e < 8; ++e){
    redS[pg][cg+e] = s[e];
    redQ[pg][cg+e] = q[e];
  }
  __syncthreads();
  float ssum = 0.f, qsum = 0.f;
#pragma unroll
  for (int p = 0; p < 8; ++p){ ssum += redS[p][tid]; qsum += redQ[p][tid]; }
  atomicAdd(&st[1536 + tid], (double)ssum);
  atomicAdd(&st[1792 + tid], (double)qsum);
}

// --------------------------------------------------------------- softmax
// 256 blocks (16,4,4): chunk = 256 rows x 64 ch. FP16 yout, 8 ch/thread.
__global__ __launch_bounds__(256)
void k_soft1(const __half* __restrict__ yout, const double* __restrict__ st,
             const float* __restrict__ g1, float* __restrict__ sums){
  __shared__ float redL[32][64];
  __shared__ float sA[64], sK[64];
  int tid = threadIdx.x;
  int chunk = blockIdx.x, ct = blockIdx.y, b = blockIdx.z;
  int cg = (tid & 7)*8, pg = tid >> 3;         // 8 ch-groups x 32 px-groups
  if (tid < 64){
    int cc = ct*64 + tid;
    double mu  = st[1536 + cc]*(1.0/NTOT);
    double var = st[1792 + cc]*(1.0/NTOT) - mu*mu;
    double a = g1[cc] / sqrt(var + EPS);
    sA[tid] = (float)a;
    sK[tid] = (float)(a*mu);
  }
  __syncthreads();
  float av[8], Kv[8];
#pragma unroll
  for (int e = 0; e < 8; ++e){ av[e] = sA[cg+e]; Kv[e] = sK[cg+e]; }
  const __half* base = yout + ((size_t)b*4096 + chunk*256)*256 + ct*64 + cg;
  float s[8] = {0,0,0,0,0,0,0,0};
#pragma unroll
  for (int k = 0; k < 8; ++k){
    uint4 u = *(const uint4*)(base + (size_t)(pg + k*32)*256);
    const unsigned short* up = (const unsigned short*)&u;
#pragma unroll
    for (int e = 0; e < 8; ++e)
      s[e] += __expf(h2f(up[e])*av[e] - Kv[e]);
  }
#pragma unroll
  for (int e = 0; e < 8; ++e) redL[pg][cg+e] = s[e];
  __syncthreads();
  if (tid < 64){
    float tot = 0.f;
#pragma unroll
    for (int p = 0; p < 32; ++p) tot += redL[p][tid];
    atomicAdd(&sums[b*256 + ct*64 + tid], tot);
  }
}

__global__ __launch_bounds__(256)
void k_soft2(const __half* __restrict__ yout, const double* __restrict__ st,
             const float* __restrict__ g1, const float* __restrict__ sums,
             float* __restrict__ out){
  __shared__ float sA[64], sK[64], sR[64];
  int tid = threadIdx.x;
  int chunk = blockIdx.x, ct = blockIdx.y, b = blockIdx.z;
  int cg = (tid & 7)*8, pg = tid >> 3;
  if (tid < 64){
    int cc = ct*64 + tid;
    double mu  = st[1536 + cc]*(1.0/NTOT);
    double var = st[1792 + cc]*(1.0/NTOT) - mu*mu;
    double a = g1[cc] / sqrt(var + EPS);
    sA[tid] = (float)a;
    sK[tid] = (float)(a*mu);
    sR[tid] = 1.f / sums[b*256 + cc];
  }
  __syncthreads();
  float av[8], Kv[8], rv[8];
#pragma unroll
  for (int e = 0; e < 8; ++e){ av[e] = sA[cg+e]; Kv[e] = sK[cg+e]; rv[e] = sR[cg+e]; }
  const __half* base = yout + ((size_t)b*4096 + chunk*256)*256 + ct*64 + cg;
  float* obase = out + ((size_t)b*4096 + chunk*256)*256 + ct*64 + cg;
#pragma unroll
  for (int k = 0; k < 8; ++k){
    size_t off = (size_t)(pg + k*32)*256;
    uint4 u = *(const uint4*)(base + off);
    const unsigned short* up = (const unsigned short*)&u;
    float o[8];
#pragma unroll
    for (int e = 0; e < 8; ++e)
      o[e] = __expf(h2f(up[e])*av[e] - Kv[e]) * rv[e];
    float4 o0; o0.x = o[0]; o0.y = o[1]; o0.z = o[2]; o0.w = o[3];
    float4 o1; o1.x = o[4]; o1.y = o[5]; o1.z = o[6]; o1.w = o[7];
    *(float4*)(obase + off)     = o0;
    *(float4*)(obase + off + 4) = o1;
  }
}

// ---------------------------------------------------------------------------
extern "C" void kernel_launch(void* const* d_in, const int* in_sizes, int n_in,
                              void* d_out, int out_size, void* d_ws, size_t ws_size,
                              hipStream_t stream){
  (void)in_sizes; (void)n_in; (void)out_size; (void)ws_size;
  const float* X  = (const float*)d_in[0];
  const float* Wq = (const float*)d_in[1];
  const float* gq = (const float*)d_in[2];
  const float* bq = (const float*)d_in[3];
  const float* Wk = (const float*)d_in[4];
  const float* gk = (const float*)d_in[5];
  const float* bk = (const float*)d_in[6];
  const float* Wv = (const float*)d_in[7];
  const float* gv = (const float*)d_in[8];
  const float* bv = (const float*)d_in[9];
  const float* g1 = (const float*)d_in[10];
  // d_in[11] = b1: cancels inside the spatial softmax

  char* ws = (char*)d_ws;
  double*         st   = (double*)ws;                        // 2048 f64 (16KB)
  float*          sums = (float*)(ws + 16384);               // 4KB
  unsigned short* Wt   = (unsigned short*)(ws + 26624);      // 768x256 bf16 -> ends 419840
  unsigned short* Xb   = (unsigned short*)(ws + 419840);     // 8MB -> ends 8808448
  unsigned short* YQK  = (unsigned short*)(ws + 8808448);    // 16MB bf16 frag-major -> 25585664
  unsigned short* Yv   = (unsigned short*)(ws + 25585664);   // 8MB bf16 row-major -> 33974272
  unsigned short* Kf   = (unsigned short*)(ws + 33974272);   // 8MB frag-major -> 42362880
  unsigned short* Vf   = (unsigned short*)(ws + 42362880);   // 8MB frag-major -> 50751488
  __half*         P1   = (__half*)(ws + 50751488);           // 8.4MB (fp16)
  // overlays: Qf on Xb (dead after GEMM); P0 on YQK (dead after bn);
  // yout on Kf+Vf (dead after attn)
  unsigned short* Qf   = Xb;
  __half*         P0   = (__half*)(ws + 8808448);
  __half*         yo   = (__half*)(ws + 33974272);

  k_prep    <<<4864, 256, 0, stream>>>(X, Wq, Wk, Wv, Xb, Wt, (float*)st);
  k_qkv_gemm<<<768, 256, 0, stream>>>(Xb, Wt, YQK, Yv, st);
  k_bn      <<<5120, 256, 0, stream>>>(YQK, Yv, st, gq, bq, gk, bk, gv, bv, Qf, Kf, Vf);
  k_attn    <<<512, 512, 0, stream>>>(Qf, Kf, Vf, P0, P1);
  k_red     <<<512, 256, 0, stream>>>(P0, P1, yo, st);
  k_soft1   <<<dim3(16,4,4), 256, 0, stream>>>(yo, st, g1, sums);
  k_soft2   <<<dim3(16,4,4), 256, 0, stream>>>(yo, st, g1, sums, (float*)d_out);
}

// Round 15
// 226.933 us; speedup vs baseline: 1.4067x; 1.4067x over previous
//
#include <hip/hip_runtime.h>
#include <hip/hip_fp16.h>
#include <stdint.h>

// ---------------------------------------------------------------------------
// GroupAttentionLayer: RF=16,STRIDE=16 windows tile the image exactly =>
//   yout = leaky(Q K^T / 16) V  (full dense attention per batch), then BN +
//   spatial softmax (mu/beta cancel; only a_c = g1/sqrt(var+eps) survives).
// B=4, P=4096 px/batch (T=16384 rows), C=256. Inputs fp32, OUTPUT fp32.
// R7:  k_attn operands FRAGMENT-MAJOR in global (lane-contiguous 1KB loads).
// R8:  BN stats fused into GEMM epilogue; frag-major YQK; setprio (+7%).
// R9:  launch fusion (7 kernels); coefs inline in k_bn; 1/16 into Q coefs.
// R10: q-tile 128 -> SLOWER (latency-bound at 1 blk/CU). REVERTED.
// R11: Gram-matrix analytic stats -> REGRESSION. REVERTED.
// R12: split-K fusion w/ __threadfence -> CATASTROPHIC (L2 flush). REVERTED.
// R13: cooperative grid.sync tail -> 105us for 50MB. REVERTED.
// R14: float4 tail + gemm grid swap -> 242.7us.
// R15: bf16 Y + XCD-pinned gemm + vectorized k_bn V -> 240.95us.
// R16: m97-structure QKV GEMM -> 230.0us; absmax 1.22e-4.
// R17: attn V-prefetch -> spill REGRESSION. REVERTED.
// R18: soft 1024-blk -> noise. Reverted.
// R19: swapped-QK^T S-convert (cvt_pk+permlane) -> time-null. Kept.
// R20: FP16 tail intermediates -> 226.1us (BEST); absmax 1.83e-4.
// R21: single-barrier attn (Ql dropped, Sl dbuf) -> CATASTROPHIC: FETCH
//      16.4->387MB (8 waves x 8 kt re-read the shared Q tile from global;
//      L2 4MB/XCD already at capacity). REVERTED. Lesson: Ql LDS staging
//      is what makes 8-wave Q reuse free; no LDS budget for Ql + Sl-dbuf
//      at 2 blocks/CU.
// R22 (this round): exact revert to R20 (best measured). Experiment ledger
//      exhausted for verified-safe levers; re-establishing best state.
//   Qf/Kf[((g*16+ks)*64+lane)*8+j] : row=g*32+(lane&31), ch=ks*16+(lane>>5)*8+j
//   Vf[((gc*256+kp)*64+lane)*8+j]  : ch=(gc&7)*32+(lane&31), key=kp*16+(lane>>5)*8+j
// ---------------------------------------------------------------------------

typedef __attribute__((ext_vector_type(8)))  short short8;   // 8 x bf16
typedef __attribute__((ext_vector_type(4)))  float f32x4;    // 16x16 acc
typedef __attribute__((ext_vector_type(16))) float f32x16;   // 32x32 acc
typedef __attribute__((ext_vector_type(4)))  unsigned short ushort4v;

#define ALPHA 0.3f
#define EPS   1e-3
#define NTOT  16384.0

#define GLOAD_LDS16(gp, lp) __builtin_amdgcn_global_load_lds( \
    (const __attribute__((address_space(1))) void*)(gp), \
    (__attribute__((address_space(3))) void*)(lp), 16, 0, 0)

__device__ __forceinline__ unsigned short f2bf(float f){
  unsigned u = __float_as_uint(f);
  u += 0x7FFFu + ((u>>16)&1u);          // RNE
  return (unsigned short)(u>>16);
}
__device__ __forceinline__ float bf2f(unsigned short u){
  return __uint_as_float((unsigned)u << 16);
}
__device__ __forceinline__ float lrelu(float x){ return fmaxf(x, ALPHA*x); }
__device__ __forceinline__ float h2f(unsigned short u){
  return __half2float(__ushort_as_half(u));
}
__device__ __forceinline__ unsigned short f2h(float f){
  return __half_as_ushort(__float2half(f));
}

// ------------------------------------------------- prep: cvt + wtrans + zero
__global__ __launch_bounds__(256)
void k_prep(const float* __restrict__ X,
            const float* __restrict__ Wq,
            const float* __restrict__ Wk,
            const float* __restrict__ Wv,
            unsigned short* __restrict__ Xb,
            unsigned short* __restrict__ Wt,
            float* __restrict__ zws){
  int blk = blockIdx.x, tid = threadIdx.x;
  if (blk < 4096){
    int i = (blk*256 + tid)*4;
    float4 v = *(const float4*)(X + i);
    ushort4v o; o.x = f2bf(v.x); o.y = f2bf(v.y); o.z = f2bf(v.z); o.w = f2bf(v.w);
    *(ushort4v*)(Xb + i) = o;
  } else {
    int o = (blk - 4096)*256 + tid;              // 0 .. 196607
    int p = o >> 16, rem = o & 65535;
    int j = rem >> 8, c = rem & 255;
    const float* W = (p==0) ? Wq : ((p==1) ? Wk : Wv);
    Wt[o] = f2bf(W[c*256 + j]);
    if (o < 5120) zws[o] = 0.f;                  // st + sums
  }
}

// --------------------------------------------------------------- QKV GEMM
// m97 structure: 128x128 tile, BK=64, 768 blocks (xcd-pinned), 4 waves.
// A/B staged via global_load_lds dwordx4 into linear [128][64] LDS.
// Q/K planes (nb<4) -> frag-major BF16 YQK; V (nb>=4) -> row-major BF16 Yv.
// BN stats (fp32 partials -> LDS -> f64 atomics) in the epilogue.
__global__ __launch_bounds__(256)
void k_qkv_gemm(const unsigned short* __restrict__ X,
                const unsigned short* __restrict__ Wt,
                unsigned short* __restrict__ YQK, unsigned short* __restrict__ Yv,
                double* __restrict__ st){
  __shared__ __align__(16) unsigned short At[128*64];   // 16KB
  __shared__ __align__(16) unsigned short Bt[128*64];   // 16KB
  int tid = threadIdx.x;
  int g = blockIdx.x;
  int xcd = g & 7, r8 = g >> 3;          // 96 per XCD = 16 mb x 6 nb
  int mb = xcd*16 + r8/6, nb = r8 % 6;
  int lane = tid & 63, w = tid >> 6;
  int ln15 = lane & 15, quad = lane >> 4;
  int rw = (w & 1)*64, cw = (w >> 1)*64;       // 2x2 waves, 64x64 each

  const unsigned short* gaL = X  + ((size_t)(mb*128 + (lane>>3)))*256 + (lane&7)*8;
  const unsigned short* gbL = Wt + ((size_t)(nb*128 + (lane>>3)))*256 + (lane&7)*8;

  f32x4 acc[4][4] = {};
  for (int kt = 0; kt < 4; ++kt){
    const unsigned short* ga = gaL + kt*64;
    const unsigned short* gb = gbL + kt*64;
#pragma unroll
    for (int j = 0; j < 4; ++j){
      int s = w*4 + j;                         // segment 0..15
      GLOAD_LDS16(ga + (size_t)s*8*256, At + s*512);
      GLOAD_LDS16(gb + (size_t)s*8*256, Bt + s*512);
    }
    __syncthreads();
#pragma unroll
    for (int ksub = 0; ksub < 2; ++ksub){
      short8 af[4], bf[4];
#pragma unroll
      for (int mt = 0; mt < 4; ++mt)
        af[mt] = *(const short8*)(At + (rw + mt*16 + ln15)*64 + ksub*32 + quad*8);
#pragma unroll
      for (int nt = 0; nt < 4; ++nt)
        bf[nt] = *(const short8*)(Bt + (cw + nt*16 + ln15)*64 + ksub*32 + quad*8);
#pragma unroll
      for (int mt = 0; mt < 4; ++mt)
#pragma unroll
        for (int nt = 0; nt < 4; ++nt)
          acc[mt][nt] = __builtin_amdgcn_mfma_f32_16x16x32_bf16(af[mt], bf[nt], acc[mt][nt], 0,0,0);
    }
    __syncthreads();
  }
  // ---- per-lane column partials for BN stats (raw fp32 Y values)
  float ps[4] = {0,0,0,0}, pq[4] = {0,0,0,0};
#pragma unroll
  for (int mt = 0; mt < 4; ++mt)
#pragma unroll
    for (int nt = 0; nt < 4; ++nt)
#pragma unroll
      for (int rr = 0; rr < 4; ++rr){
        float v = acc[mt][nt][rr];
        ps[nt] += v; pq[nt] += v*v;
      }
  // ---- C-store (bf16)
  if (nb < 4){
    int proj = nb >> 1;                        // 0=Q (nb 0,1), 1=K (nb 2,3)
    unsigned short* base = YQK + (size_t)proj*(16384*256);
#pragma unroll
    for (int nt = 0; nt < 4; ++nt){
      int ch_g = (nb&1)*128 + cw + nt*16 + ln15;
      int ksf = ch_g >> 4, l5c = (ch_g >> 3) & 1, j = ch_g & 7;
#pragma unroll
      for (int mt = 0; mt < 4; ++mt){
        int row0 = mb*128 + rw + mt*16 + quad*4;
        int gg = row0 >> 5, l31r0 = row0 & 31;
#pragma unroll
        for (int rr = 0; rr < 4; ++rr){
          size_t chunk = (size_t)((gg*16 + ksf)*64 + l5c*32 + l31r0 + rr);
          base[chunk*8 + j] = f2bf(acc[mt][nt][rr]);
        }
      }
    }
  } else {
    int vc0 = (nb - 4)*128 + cw;
#pragma unroll
    for (int mt = 0; mt < 4; ++mt)
#pragma unroll
      for (int nt = 0; nt < 4; ++nt)
#pragma unroll
        for (int rr = 0; rr < 4; ++rr){
          int row = mb*128 + rw + mt*16 + quad*4 + rr;
          Yv[(size_t)row*256 + vc0 + nt*16 + ln15] = f2bf(acc[mt][nt][rr]);
        }
  }
  // ---- stats reduce: LDS (reuse At, 256 f32) then f64 atomics per channel
  __syncthreads();
  float* red = (float*)At;                     // [0..128) sum, [128..256) sq
  red[tid] = 0.f;
  __syncthreads();
#pragma unroll
  for (int nt = 0; nt < 4; ++nt){
    int colL = cw + nt*16 + ln15;              // 0..127
    atomicAdd(&red[colL],       ps[nt]);
    atomicAdd(&red[128 + colL], pq[nt]);
  }
  __syncthreads();
  if (tid < 128){
    int cc = nb*128 + tid;                     // global channel 0..767
    atomicAdd(&st[cc],       (double)red[tid]);
    atomicAdd(&st[768 + cc], (double)red[128 + tid]);
  }
}

// ------------------------------------------------- BN+leaky: Q,K frag stream
// + V transpose, one dispatch. Coefs computed inline from st. Y is BF16.
// Q coefs carry an extra 1/16 (score scale folded in; exact exponent shift).
__global__ __launch_bounds__(256)
void k_bn(const unsigned short* __restrict__ YQK, const unsigned short* __restrict__ Yv,
          const double* __restrict__ st,
          const float* __restrict__ gq, const float* __restrict__ bq,
          const float* __restrict__ gk, const float* __restrict__ bk,
          const float* __restrict__ gv, const float* __restrict__ bv,
          unsigned short* __restrict__ Qf, unsigned short* __restrict__ Kf,
          unsigned short* __restrict__ Vf){
  __shared__ float sc_s[256], sh_s[256];
  __shared__ unsigned short tile[64][66];
  int tid = threadIdx.x;
  int blk = blockIdx.x;
  if (blk < 4096){
    int proj = blk >> 11;                        // 2048 blocks per proj (0=Q,1=K)
    {
      int c = tid;
      int cc = proj*256 + c;
      double mu  = st[cc]     * (1.0/NTOT);
      double var = st[768+cc] * (1.0/NTOT) - mu*mu;
      double g = proj ? (double)gk[c] : (double)gq[c];
      double b = proj ? (double)bk[c] : (double)bq[c];
      double a = g / sqrt(var + EPS);
      float f = proj ? 1.f : 0.0625f;            // fold 1/16 into Q
      sc_s[c] = (float)a * f;
      sh_s[c] = (float)(b - mu*a) * f;
    }
    __syncthreads();
    int oc = blk*256 + tid;                      // chunk of 8 bf16 values
    int rest = oc & 524287;
    int ks = (rest >> 6) & 15, l5c = (rest >> 5) & 1;
    int ch0 = ks*16 + l5c*8;
    uint4 yin = *(const uint4*)(YQK + (size_t)oc*8);
    const unsigned short* yp = (const unsigned short*)&yin;
    const float* sc = sc_s + ch0;
    const float* sh = sh_s + ch0;
    unsigned short rr[8];
#pragma unroll
    for (int e = 0; e < 8; ++e){
      float v = bf2f(yp[e]);
      rr[e] = f2bf(lrelu(v*sc[e] + sh[e]));
    }
    uint4 u;
    u.x = (unsigned)rr[0] | ((unsigned)rr[1]<<16);
    u.y = (unsigned)rr[2] | ((unsigned)rr[3]<<16);
    u.z = (unsigned)rr[4] | ((unsigned)rr[5]<<16);
    u.w = (unsigned)rr[6] | ((unsigned)rr[7]<<16);
    *(uint4*)((proj ? Kf : Qf) + (size_t)rest*8) = u;
  } else {
    int b2 = blk - 4096;
    int pt = b2 & 63, ct = (b2 >> 6) & 3, b = b2 >> 8;
    if (tid < 64){
      int c = ct*64 + tid;
      int cc = 512 + c;
      double mu  = st[cc]     * (1.0/NTOT);
      double var = st[768+cc] * (1.0/NTOT) - mu*mu;
      double a = (double)gv[c] / sqrt(var + EPS);
      sc_s[tid] = (float)a;
      sh_s[tid] = (float)((double)bv[c] - mu*a);
    }
    __syncthreads();
#pragma unroll
    for (int kpass = 0; kpass < 2; ++kpass){
      int idx = kpass*256 + tid;                 // 0..511
      int px = idx >> 3, co = idx & 7;
      size_t t = (size_t)b*4096 + pt*64 + px;
      uint4 u = *(const uint4*)(Yv + t*256 + ct*64 + co*8);
      const unsigned short* up = (const unsigned short*)&u;
      int c0 = co*8;
#pragma unroll
      for (int e = 0; e < 8; ++e){
        float v = bf2f(up[e]);
        tile[px][c0+e] = f2bf(lrelu(v*sc_s[c0+e] + sh_s[c0+e]));
      }
    }
    __syncthreads();
#pragma unroll
    for (int it = 0; it < 2; ++it){
      int m = it*256 + tid;                      // 512 chunks of 8 keys
      int c2 = m >> 3, kg = m & 7;
      int ch = ct*64 + c2;
      int gc = b*8 + (ch >> 5), l31c = ch & 31;
      int kp = pt*4 + (kg >> 1), l5k = kg & 1;
      unsigned short r0 = tile[kg*8+0][c2], r1 = tile[kg*8+1][c2];
      unsigned short r2 = tile[kg*8+2][c2], r3 = tile[kg*8+3][c2];
      unsigned short r4 = tile[kg*8+4][c2], r5 = tile[kg*8+5][c2];
      unsigned short r6 = tile[kg*8+6][c2], r7 = tile[kg*8+7][c2];
      uint4 u;
      u.x = (unsigned)r0 | ((unsigned)r1<<16);
      u.y = (unsigned)r2 | ((unsigned)r3<<16);
      u.z = (unsigned)r4 | ((unsigned)r5<<16);
      u.w = (unsigned)r6 | ((unsigned)r7<<16);
      *(uint4*)(Vf + ((size_t)((gc*256 + kp)*64 + l5k*32 + l31c))*8) = u;
    }
  }
}

// --------------------------------------------------------------- attention
// R20 state (best measured): R16 structure + R19 swapped-QK^T S-convert;
// P stored FP16. 512 blocks x 512 threads, q-tile 64. blk&7 = (b,half) ->
// XCD-pinned. 8 iters of BK=256, 2 barriers/iter. setprio(1) wraps MFMA.
__global__ __launch_bounds__(512, 4)
void k_attn(const unsigned short* __restrict__ Qf,
            const unsigned short* __restrict__ Kf,
            const unsigned short* __restrict__ Vf,
            __half* __restrict__ P0, __half* __restrict__ P1){
  __shared__ __align__(16) unsigned short Ql[64*256];   // frag-major Q tile
  __shared__ __align__(16) unsigned short Sl[64*264];   // [q][key] padded
  int tid = threadIdx.x;
  int blk = blockIdx.x;
  int qt = blk >> 3, combo = blk & 7;
  int b = combo >> 1, half = combo & 1;
  int q0 = qt*64;
  int lane = tid & 63, w = tid >> 6;
  int l31 = lane & 31, l5 = lane >> 5;
  __half* P = half ? P1 : P0;

  int gq0 = b*128 + qt*2;
  {
    const uint4* src = (const uint4*)(Qf + (size_t)gq0*8192);
    uint4* dst = (uint4*)Ql;
#pragma unroll
    for (int it = 0; it < 4; ++it) dst[it*512 + tid] = src[it*512 + tid];
  }
  __syncthreads();

  f32x16 acc2[2] = {};
  int gk0 = b*128 + half*64 + w;
  const unsigned short* kb = Kf + (size_t)gk0*8192 + lane*8;
  const unsigned short* vb = Vf + ((size_t)((b*8 + w)*256 + half*128))*512 + lane*8;
  const unsigned short* qa0 = Ql + lane*8;
  const unsigned short* qa1 = Ql + 16*512 + lane*8;

  for (int kt = 0; kt < 8; ++kt){
    f32x16 a1[2] = {};
    const unsigned short* kbt = kb + (size_t)kt*8*8192;
    __builtin_amdgcn_s_setprio(1);
#pragma unroll
    for (int ks = 0; ks < 16; ++ks){
      short8 kf = *(const short8*)(kbt + ks*512);
      short8 q0v = *(const short8*)(qa0 + ks*512);
      short8 q1v = *(const short8*)(qa1 + ks*512);
      a1[0] = __builtin_amdgcn_mfma_f32_32x32x16_bf16(kf, q0v, a1[0], 0, 0, 0);
      a1[1] = __builtin_amdgcn_mfma_f32_32x32x16_bf16(kf, q1v, a1[1], 0, 0, 0);
    }
    __builtin_amdgcn_s_setprio(0);
    __syncthreads();     // B0: all waves done reading Sl of iter kt-1
#pragma unroll
    for (int c = 0; c < 2; ++c){
      float t[16];
#pragma unroll
      for (int r = 0; r < 16; ++r){
        float x = a1[c][r];
        t[r] = fmaxf(x, 0.3f*x);
      }
      unsigned p0,p1,p2,p3,p4,p5,p6,p7;
      asm("v_cvt_pk_bf16_f32 %0, %1, %2" : "=v"(p0) : "v"(t[0]),  "v"(t[1]));
      asm("v_cvt_pk_bf16_f32 %0, %1, %2" : "=v"(p1) : "v"(t[2]),  "v"(t[3]));
      asm("v_cvt_pk_bf16_f32 %0, %1, %2" : "=v"(p2) : "v"(t[4]),  "v"(t[5]));
      asm("v_cvt_pk_bf16_f32 %0, %1, %2" : "=v"(p3) : "v"(t[6]),  "v"(t[7]));
      asm("v_cvt_pk_bf16_f32 %0, %1, %2" : "=v"(p4) : "v"(t[8]),  "v"(t[9]));
      asm("v_cvt_pk_bf16_f32 %0, %1, %2" : "=v"(p5) : "v"(t[10]), "v"(t[11]));
      asm("v_cvt_pk_bf16_f32 %0, %1, %2" : "=v"(p6) : "v"(t[12]), "v"(t[13]));
      asm("v_cvt_pk_bf16_f32 %0, %1, %2" : "=v"(p7) : "v"(t[14]), "v"(t[15]));
      asm volatile("v_permlane32_swap_b32 %0, %1" : "+v"(p0), "+v"(p4));
      asm volatile("v_permlane32_swap_b32 %0, %1" : "+v"(p1), "+v"(p5));
      asm volatile("v_permlane32_swap_b32 %0, %1" : "+v"(p2), "+v"(p6));
      asm volatile("v_permlane32_swap_b32 %0, %1" : "+v"(p3), "+v"(p7));
      uint4 u0; u0.x = p0; u0.y = p1; u0.z = p4; u0.w = p5;   // keys +0..7
      uint4 u1; u1.x = p2; u1.y = p3; u1.z = p6; u1.w = p7;   // keys +8..15
      unsigned short* dstp = Sl + (c*32 + l31)*264 + w*32 + l5*16;
      *(uint4*)(dstp)     = u0;
      *(uint4*)(dstp + 8) = u1;
    }
    __syncthreads();     // B1: S visible
    const unsigned short* vbt = vb + (size_t)kt*16*512;
    __builtin_amdgcn_s_setprio(1);
#pragma unroll
    for (int kk = 0; kk < 16; ++kk){
      short8 vf = *(const short8*)(vbt + kk*512);
      short8 s0 = *(const short8*)(Sl + (     l31)*264 + kk*16 + l5*8);
      short8 s1 = *(const short8*)(Sl + (32 + l31)*264 + kk*16 + l5*8);
      acc2[0] = __builtin_amdgcn_mfma_f32_32x32x16_bf16(s0, vf, acc2[0], 0, 0, 0);
      acc2[1] = __builtin_amdgcn_mfma_f32_32x32x16_bf16(s1, vf, acc2[1], 0, 0, 0);
    }
    __builtin_amdgcn_s_setprio(0);
  }
#pragma unroll
  for (int c = 0; c < 2; ++c)
#pragma unroll
    for (int reg = 0; reg < 16; ++reg){
      int row = q0 + c*32 + (reg & 3) + 8*(reg >> 2) + 4*l5;
      P[((size_t)b*4096 + row)*256 + w*32 + l31] = __float2half(acc2[c][reg]);
    }
}

// ------------------------------------------------- partial reduce + BN stats
// 512 blocks x 32 rows. FP16 in/out: thread owns 8 consecutive channels
// (16B/lane); f32 partials -> LDS -> f64 atomics (same accumulation class).
__global__ __launch_bounds__(256)
void k_red(const __half* __restrict__ P0, const __half* __restrict__ P1,
           __half* __restrict__ yout, double* __restrict__ st){
  __shared__ float redS[8][256];
  __shared__ float redQ[8][256];
  int tid = threadIdx.x;
  int cg = (tid & 31)*8, pg = tid >> 5;        // 32 ch-groups x 8 px-groups
  int r0 = blockIdx.x*32;
  float s[8] = {0,0,0,0,0,0,0,0}, q[8] = {0,0,0,0,0,0,0,0};
#pragma unroll
  for (int k = 0; k < 4; ++k){
    size_t idx = (size_t)(r0 + pg + k*8)*256 + cg;
    uint4 ua = *(const uint4*)(P0 + idx);
    uint4 ub = *(const uint4*)(P1 + idx);
    const unsigned short* pa = (const unsigned short*)&ua;
    const unsigned short* pb = (const unsigned short*)&ub;
    unsigned short ho[8];
#pragma unroll
    for (int e = 0; e < 8; ++e){
      float v = h2f(pa[e]) + h2f(pb[e]);
      ho[e] = f2h(v);
      s[e] += v; q[e] += v*v;
    }
    uint4 uo;
    uo.x = (unsigned)ho[0] | ((unsigned)ho[1]<<16);
    uo.y = (unsigned)ho[2] | ((unsigned)ho[3]<<16);
    uo.z = (unsigned)ho[4] | ((unsigned)ho[5]<<16);
    uo.w = (unsigned)ho[6] | ((unsigned)ho[7]<<16);
    *(uint4*)(yout + idx) = uo;
  }
#pragma unroll
  for (int e = 0; e < 8; ++e){
    redS[pg][cg+e] = s[e];
    redQ[pg][cg+e] = q[e];
  }
  __syncthreads();
  float ssum = 0.f, qsum = 0.f;
#pragma unroll
  for (int p = 0; p < 8; ++p){ ssum += redS[p][tid]; qsum += redQ[p][tid]; }
  atomicAdd(&st[1536 + tid], (double)ssum);
  atomicAdd(&st[1792 + tid], (double)qsum);
}

// --------------------------------------------------------------- softmax
// 256 blocks (16,4,4): chunk = 256 rows x 64 ch. FP16 yout, 8 ch/thread.
__global__ __launch_bounds__(256)
void k_soft1(const __half* __restrict__ yout, const double* __restrict__ st,
             const float* __restrict__ g1, float* __restrict__ sums){
  __shared__ float redL[32][64];
  __shared__ float sA[64], sK[64];
  int tid = threadIdx.x;
  int chunk = blockIdx.x, ct = blockIdx.y, b = blockIdx.z;
  int cg = (tid & 7)*8, pg = tid >> 3;         // 8 ch-groups x 32 px-groups
  if (tid < 64){
    int cc = ct*64 + tid;
    double mu  = st[1536 + cc]*(1.0/NTOT);
    double var = st[1792 + cc]*(1.0/NTOT) - mu*mu;
    double a = g1[cc] / sqrt(var + EPS);
    sA[tid] = (float)a;
    sK[tid] = (float)(a*mu);
  }
  __syncthreads();
  float av[8], Kv[8];
#pragma unroll
  for (int e = 0; e < 8; ++e){ av[e] = sA[cg+e]; Kv[e] = sK[cg+e]; }
  const __half* base = yout + ((size_t)b*4096 + chunk*256)*256 + ct*64 + cg;
  float s[8] = {0,0,0,0,0,0,0,0};
#pragma unroll
  for (int k = 0; k < 8; ++k){
    uint4 u = *(const uint4*)(base + (size_t)(pg + k*32)*256);
    const unsigned short* up = (const unsigned short*)&u;
#pragma unroll
    for (int e = 0; e < 8; ++e)
      s[e] += __expf(h2f(up[e])*av[e] - Kv[e]);
  }
#pragma unroll
  for (int e = 0; e < 8; ++e) redL[pg][cg+e] = s[e];
  __syncthreads();
  if (tid < 64){
    float tot = 0.f;
#pragma unroll
    for (int p = 0; p < 32; ++p) tot += redL[p][tid];
    atomicAdd(&sums[b*256 + ct*64 + tid], tot);
  }
}

__global__ __launch_bounds__(256)
void k_soft2(const __half* __restrict__ yout, const double* __restrict__ st,
             const float* __restrict__ g1, const float* __restrict__ sums,
             float* __restrict__ out){
  __shared__ float sA[64], sK[64], sR[64];
  int tid = threadIdx.x;
  int chunk = blockIdx.x, ct = blockIdx.y, b = blockIdx.z;
  int cg = (tid & 7)*8, pg = tid >> 3;
  if (tid < 64){
    int cc = ct*64 + tid;
    double mu  = st[1536 + cc]*(1.0/NTOT);
    double var = st[1792 + cc]*(1.0/NTOT) - mu*mu;
    double a = g1[cc] / sqrt(var + EPS);
    sA[tid] = (float)a;
    sK[tid] = (float)(a*mu);
    sR[tid] = 1.f / sums[b*256 + cc];
  }
  __syncthreads();
  float av[8], Kv[8], rv[8];
#pragma unroll
  for (int e = 0; e < 8; ++e){ av[e] = sA[cg+e]; Kv[e] = sK[cg+e]; rv[e] = sR[cg+e]; }
  const __half* base = yout + ((size_t)b*4096 + chunk*256)*256 + ct*64 + cg;
  float* obase = out + ((size_t)b*4096 + chunk*256)*256 + ct*64 + cg;
#pragma unroll
  for (int k = 0; k < 8; ++k){
    size_t off = (size_t)(pg + k*32)*256;
    uint4 u = *(const uint4*)(base + off);
    const unsigned short* up = (const unsigned short*)&u;
    float o[8];
#pragma unroll
    for (int e = 0; e < 8; ++e)
      o[e] = __expf(h2f(up[e])*av[e] - Kv[e]) * rv[e];
    float4 o0; o0.x = o[0]; o0.y = o[1]; o0.z = o[2]; o0.w = o[3];
    float4 o1; o1.x = o[4]; o1.y = o[5]; o1.z = o[6]; o1.w = o[7];
    *(float4*)(obase + off)     = o0;
    *(float4*)(obase + off + 4) = o1;
  }
}

// ---------------------------------------------------------------------------
extern "C" void kernel_launch(void* const* d_in, const int* in_sizes, int n_in,
                              void* d_out, int out_size, void* d_ws, size_t ws_size,
                              hipStream_t stream){
  (void)in_sizes; (void)n_in; (void)out_size; (void)ws_size;
  const float* X  = (const float*)d_in[0];
  const float* Wq = (const float*)d_in[1];
  const float* gq = (const float*)d_in[2];
  const float* bq = (const float*)d_in[3];
  const float* Wk = (const float*)d_in[4];
  const float* gk = (const float*)d_in[5];
  const float* bk = (const float*)d_in[6];
  const float* Wv = (const float*)d_in[7];
  const float* gv = (const float*)d_in[8];
  const float* bv = (const float*)d_in[9];
  const float* g1 = (const float*)d_in[10];
  // d_in[11] = b1: cancels inside the spatial softmax

  char* ws = (char*)d_ws;
  double*         st   = (double*)ws;                        // 2048 f64 (16KB)
  float*          sums = (float*)(ws + 16384);               // 4KB
  unsigned short* Wt   = (unsigned short*)(ws + 26624);      // 768x256 bf16 -> ends 419840
  unsigned short* Xb   = (unsigned short*)(ws + 419840);     // 8MB -> ends 8808448
  unsigned short* YQK  = (unsigned short*)(ws + 8808448);    // 16MB bf16 frag-major -> 25585664
  unsigned short* Yv   = (unsigned short*)(ws + 25585664);   // 8MB bf16 row-major -> 33974272
  unsigned short* Kf   = (unsigned short*)(ws + 33974272);   // 8MB frag-major -> 42362880
  unsigned short* Vf   = (unsigned short*)(ws + 42362880);   // 8MB frag-major -> 50751488
  __half*         P1   = (__half*)(ws + 50751488);           // 8.4MB (fp16)
  // overlays: Qf on Xb (dead after GEMM); P0 on YQK (dead after bn);
  // yout on Kf+Vf (dead after attn)
  unsigned short* Qf   = Xb;
  __half*         P0   = (__half*)(ws + 8808448);
  __half*         yo   = (__half*)(ws + 33974272);

  k_prep    <<<4864, 256, 0, stream>>>(X, Wq, Wk, Wv, Xb, Wt, (float*)st);
  k_qkv_gemm<<<768, 256, 0, stream>>>(Xb, Wt, YQK, Yv, st);
  k_bn      <<<5120, 256, 0, stream>>>(YQK, Yv, st, gq, bq, gk, bk, gv, bv, Qf, Kf, Vf);
  k_attn    <<<512, 512, 0, stream>>>(Qf, Kf, Vf, P0, P1);
  k_red     <<<512, 256, 0, stream>>>(P0, P1, yo, st);
  k_soft1   <<<dim3(16,4,4), 256, 0, stream>>>(yo, st, g1, sums);
  k_soft2   <<<dim3(16,4,4), 256, 0, stream>>>(yo, st, g1, sums, (float*)d_out);
}

// Round 16
// 224.087 us; speedup vs baseline: 1.4246x; 1.0127x over previous
//
#include <hip/hip_runtime.h>
#include <hip/hip_fp16.h>
#include <stdint.h>

// ---------------------------------------------------------------------------
// GroupAttentionLayer: RF=16,STRIDE=16 windows tile the image exactly =>
//   yout = leaky(Q K^T / 16) V  (full dense attention per batch), then BN +
//   spatial softmax (mu/beta cancel; only a_c = g1/sqrt(var+eps) survives).
// B=4, P=4096 px/batch (T=16384 rows), C=256. Inputs fp32, OUTPUT fp32.
// R7:  k_attn operands FRAGMENT-MAJOR in global (lane-contiguous 1KB loads).
// R8:  BN stats fused into GEMM epilogue; frag-major YQK; setprio (+7%).
// R9:  launch fusion (7 kernels); coefs inline in k_bn; 1/16 into Q coefs.
// R10: q-tile 128 -> SLOWER (latency-bound at 1 blk/CU). REVERTED.
// R11: Gram-matrix analytic stats -> REGRESSION. REVERTED.
// R12: split-K fusion w/ __threadfence -> CATASTROPHIC (L2 flush). REVERTED.
// R13: cooperative grid.sync tail -> 105us for 50MB. REVERTED.
// R14: float4 tail + gemm grid swap -> 242.7us.
// R15: bf16 Y + XCD-pinned gemm + vectorized k_bn V -> 240.95us.
// R16: m97-structure QKV GEMM -> 230.0us; absmax 1.22e-4.
// R17: attn V-prefetch -> spill REGRESSION. REVERTED.
// R18: soft 1024-blk -> noise. Reverted.
// R19: swapped-QK^T S-convert (cvt_pk+permlane) -> kept; attn best 72.2us.
// R20: FP16 tail intermediates -> 226.1us (BEST); absmax 1.83e-4.
// R21: single-barrier attn -> CATASTROPHIC (FETCH 16->387MB). REVERTED.
// R22: revert to R20 -> 226.9us confirmed; attn 72.2-72.4us.
// R23 (this round): k_prep W-transpose via 48 LDS 64x64 tile blocks
//   (coalesced both sides) + 1 zero block, replacing the 768-block column
//   scatter (64 x 4B segments/wave). attn + all other kernels FROZEN at
//   the best state. Expected: small (~1-3us) or in-noise; if in-noise the
//   pipeline is at its practical floor for this session's technique set.
//   Qf/Kf[((g*16+ks)*64+lane)*8+j] : row=g*32+(lane&31), ch=ks*16+(lane>>5)*8+j
//   Vf[((gc*256+kp)*64+lane)*8+j]  : ch=(gc&7)*32+(lane&31), key=kp*16+(lane>>5)*8+j
// ---------------------------------------------------------------------------

typedef __attribute__((ext_vector_type(8)))  short short8;   // 8 x bf16
typedef __attribute__((ext_vector_type(4)))  float f32x4;    // 16x16 acc
typedef __attribute__((ext_vector_type(16))) float f32x16;   // 32x32 acc
typedef __attribute__((ext_vector_type(4)))  unsigned short ushort4v;

#define ALPHA 0.3f
#define EPS   1e-3
#define NTOT  16384.0

#define GLOAD_LDS16(gp, lp) __builtin_amdgcn_global_load_lds( \
    (const __attribute__((address_space(1))) void*)(gp), \
    (__attribute__((address_space(3))) void*)(lp), 16, 0, 0)

__device__ __forceinline__ unsigned short f2bf(float f){
  unsigned u = __float_as_uint(f);
  u += 0x7FFFu + ((u>>16)&1u);          // RNE
  return (unsigned short)(u>>16);
}
__device__ __forceinline__ float bf2f(unsigned short u){
  return __uint_as_float((unsigned)u << 16);
}
__device__ __forceinline__ float lrelu(float x){ return fmaxf(x, ALPHA*x); }
__device__ __forceinline__ float h2f(unsigned short u){
  return __half2float(__ushort_as_half(u));
}
__device__ __forceinline__ unsigned short f2h(float f){
  return __half_as_ushort(__float2half(f));
}

// ------------------------------------------------- prep: cvt + wtrans + zero
// blocks [0,4096): X fp32->bf16 streaming.
// blocks [4096,4144): W transpose, one 64x64 tile per block via LDS
//   (coalesced reads of W rows, coalesced writes of Wt rows).
// block 4144: zero st+sums (5120 f32).
__global__ __launch_bounds__(256)
void k_prep(const float* __restrict__ X,
            const float* __restrict__ Wq,
            const float* __restrict__ Wk,
            const float* __restrict__ Wv,
            unsigned short* __restrict__ Xb,
            unsigned short* __restrict__ Wt,
            float* __restrict__ zws){
  __shared__ unsigned short tileW[64][65];
  int blk = blockIdx.x, tid = threadIdx.x;
  if (blk < 4096){
    int i = (blk*256 + tid)*4;
    float4 v = *(const float4*)(X + i);
    ushort4v o; o.x = f2bf(v.x); o.y = f2bf(v.y); o.z = f2bf(v.z); o.w = f2bf(v.w);
    *(ushort4v*)(Xb + i) = o;
  } else if (blk < 4144){
    int b2 = blk - 4096;                 // 0..47
    int proj = b2 >> 4, t16 = b2 & 15;
    int tc = t16 & 3, tj = t16 >> 2;     // c-tile, j-tile (64 each)
    const float* W = (proj==0) ? Wq : ((proj==1) ? Wk : Wv);
    int sub = tid >> 6, lane6 = tid & 63;
#pragma unroll
    for (int pass = 0; pass < 16; ++pass){
      int c_l = pass*4 + sub;            // 0..63
      tileW[c_l][lane6] = f2bf(W[(size_t)(tc*64 + c_l)*256 + tj*64 + lane6]);
    }
    __syncthreads();
#pragma unroll
    for (int pass = 0; pass < 16; ++pass){
      int j_l = pass*4 + sub;            // 0..63
      Wt[proj*65536 + (tj*64 + j_l)*256 + tc*64 + lane6] = tileW[lane6][j_l];
    }
  } else {
    for (int i = tid; i < 5120; i += 256) zws[i] = 0.f;   // st + sums
  }
}

// --------------------------------------------------------------- QKV GEMM
// m97 structure: 128x128 tile, BK=64, 768 blocks (xcd-pinned), 4 waves.
// A/B staged via global_load_lds dwordx4 into linear [128][64] LDS.
// Q/K planes (nb<4) -> frag-major BF16 YQK; V (nb>=4) -> row-major BF16 Yv.
// BN stats (fp32 partials -> LDS -> f64 atomics) in the epilogue.
__global__ __launch_bounds__(256)
void k_qkv_gemm(const unsigned short* __restrict__ X,
                const unsigned short* __restrict__ Wt,
                unsigned short* __restrict__ YQK, unsigned short* __restrict__ Yv,
                double* __restrict__ st){
  __shared__ __align__(16) unsigned short At[128*64];   // 16KB
  __shared__ __align__(16) unsigned short Bt[128*64];   // 16KB
  int tid = threadIdx.x;
  int g = blockIdx.x;
  int xcd = g & 7, r8 = g >> 3;          // 96 per XCD = 16 mb x 6 nb
  int mb = xcd*16 + r8/6, nb = r8 % 6;
  int lane = tid & 63, w = tid >> 6;
  int ln15 = lane & 15, quad = lane >> 4;
  int rw = (w & 1)*64, cw = (w >> 1)*64;       // 2x2 waves, 64x64 each

  const unsigned short* gaL = X  + ((size_t)(mb*128 + (lane>>3)))*256 + (lane&7)*8;
  const unsigned short* gbL = Wt + ((size_t)(nb*128 + (lane>>3)))*256 + (lane&7)*8;

  f32x4 acc[4][4] = {};
  for (int kt = 0; kt < 4; ++kt){
    const unsigned short* ga = gaL + kt*64;
    const unsigned short* gb = gbL + kt*64;
#pragma unroll
    for (int j = 0; j < 4; ++j){
      int s = w*4 + j;                         // segment 0..15
      GLOAD_LDS16(ga + (size_t)s*8*256, At + s*512);
      GLOAD_LDS16(gb + (size_t)s*8*256, Bt + s*512);
    }
    __syncthreads();
#pragma unroll
    for (int ksub = 0; ksub < 2; ++ksub){
      short8 af[4], bf[4];
#pragma unroll
      for (int mt = 0; mt < 4; ++mt)
        af[mt] = *(const short8*)(At + (rw + mt*16 + ln15)*64 + ksub*32 + quad*8);
#pragma unroll
      for (int nt = 0; nt < 4; ++nt)
        bf[nt] = *(const short8*)(Bt + (cw + nt*16 + ln15)*64 + ksub*32 + quad*8);
#pragma unroll
      for (int mt = 0; mt < 4; ++mt)
#pragma unroll
        for (int nt = 0; nt < 4; ++nt)
          acc[mt][nt] = __builtin_amdgcn_mfma_f32_16x16x32_bf16(af[mt], bf[nt], acc[mt][nt], 0,0,0);
    }
    __syncthreads();
  }
  // ---- per-lane column partials for BN stats (raw fp32 Y values)
  float ps[4] = {0,0,0,0}, pq[4] = {0,0,0,0};
#pragma unroll
  for (int mt = 0; mt < 4; ++mt)
#pragma unroll
    for (int nt = 0; nt < 4; ++nt)
#pragma unroll
      for (int rr = 0; rr < 4; ++rr){
        float v = acc[mt][nt][rr];
        ps[nt] += v; pq[nt] += v*v;
      }
  // ---- C-store (bf16)
  if (nb < 4){
    int proj = nb >> 1;                        // 0=Q (nb 0,1), 1=K (nb 2,3)
    unsigned short* base = YQK + (size_t)proj*(16384*256);
#pragma unroll
    for (int nt = 0; nt < 4; ++nt){
      int ch_g = (nb&1)*128 + cw + nt*16 + ln15;
      int ksf = ch_g >> 4, l5c = (ch_g >> 3) & 1, j = ch_g & 7;
#pragma unroll
      for (int mt = 0; mt < 4; ++mt){
        int row0 = mb*128 + rw + mt*16 + quad*4;
        int gg = row0 >> 5, l31r0 = row0 & 31;
#pragma unroll
        for (int rr = 0; rr < 4; ++rr){
          size_t chunk = (size_t)((gg*16 + ksf)*64 + l5c*32 + l31r0 + rr);
          base[chunk*8 + j] = f2bf(acc[mt][nt][rr]);
        }
      }
    }
  } else {
    int vc0 = (nb - 4)*128 + cw;
#pragma unroll
    for (int mt = 0; mt < 4; ++mt)
#pragma unroll
      for (int nt = 0; nt < 4; ++nt)
#pragma unroll
        for (int rr = 0; rr < 4; ++rr){
          int row = mb*128 + rw + mt*16 + quad*4 + rr;
          Yv[(size_t)row*256 + vc0 + nt*16 + ln15] = f2bf(acc[mt][nt][rr]);
        }
  }
  // ---- stats reduce: LDS (reuse At, 256 f32) then f64 atomics per channel
  __syncthreads();
  float* red = (float*)At;                     // [0..128) sum, [128..256) sq
  red[tid] = 0.f;
  __syncthreads();
#pragma unroll
  for (int nt = 0; nt < 4; ++nt){
    int colL = cw + nt*16 + ln15;              // 0..127
    atomicAdd(&red[colL],       ps[nt]);
    atomicAdd(&red[128 + colL], pq[nt]);
  }
  __syncthreads();
  if (tid < 128){
    int cc = nb*128 + tid;                     // global channel 0..767
    atomicAdd(&st[cc],       (double)red[tid]);
    atomicAdd(&st[768 + cc], (double)red[128 + tid]);
  }
}

// ------------------------------------------------- BN+leaky: Q,K frag stream
// + V transpose, one dispatch. Coefs computed inline from st. Y is BF16.
// Q coefs carry an extra 1/16 (score scale folded in; exact exponent shift).
__global__ __launch_bounds__(256)
void k_bn(const unsigned short* __restrict__ YQK, const unsigned short* __restrict__ Yv,
          const double* __restrict__ st,
          const float* __restrict__ gq, const float* __restrict__ bq,
          const float* __restrict__ gk, const float* __restrict__ bk,
          const float* __restrict__ gv, const float* __restrict__ bv,
          unsigned short* __restrict__ Qf, unsigned short* __restrict__ Kf,
          unsigned short* __restrict__ Vf){
  __shared__ float sc_s[256], sh_s[256];
  __shared__ unsigned short tile[64][66];
  int tid = threadIdx.x;
  int blk = blockIdx.x;
  if (blk < 4096){
    int proj = blk >> 11;                        // 2048 blocks per proj (0=Q,1=K)
    {
      int c = tid;
      int cc = proj*256 + c;
      double mu  = st[cc]     * (1.0/NTOT);
      double var = st[768+cc] * (1.0/NTOT) - mu*mu;
      double g = proj ? (double)gk[c] : (double)gq[c];
      double b = proj ? (double)bk[c] : (double)bq[c];
      double a = g / sqrt(var + EPS);
      float f = proj ? 1.f : 0.0625f;            // fold 1/16 into Q
      sc_s[c] = (float)a * f;
      sh_s[c] = (float)(b - mu*a) * f;
    }
    __syncthreads();
    int oc = blk*256 + tid;                      // chunk of 8 bf16 values
    int rest = oc & 524287;
    int ks = (rest >> 6) & 15, l5c = (rest >> 5) & 1;
    int ch0 = ks*16 + l5c*8;
    uint4 yin = *(const uint4*)(YQK + (size_t)oc*8);
    const unsigned short* yp = (const unsigned short*)&yin;
    const float* sc = sc_s + ch0;
    const float* sh = sh_s + ch0;
    unsigned short rr[8];
#pragma unroll
    for (int e = 0; e < 8; ++e){
      float v = bf2f(yp[e]);
      rr[e] = f2bf(lrelu(v*sc[e] + sh[e]));
    }
    uint4 u;
    u.x = (unsigned)rr[0] | ((unsigned)rr[1]<<16);
    u.y = (unsigned)rr[2] | ((unsigned)rr[3]<<16);
    u.z = (unsigned)rr[4] | ((unsigned)rr[5]<<16);
    u.w = (unsigned)rr[6] | ((unsigned)rr[7]<<16);
    *(uint4*)((proj ? Kf : Qf) + (size_t)rest*8) = u;
  } else {
    int b2 = blk - 4096;
    int pt = b2 & 63, ct = (b2 >> 6) & 3, b = b2 >> 8;
    if (tid < 64){
      int c = ct*64 + tid;
      int cc = 512 + c;
      double mu  = st[cc]     * (1.0/NTOT);
      double var = st[768+cc] * (1.0/NTOT) - mu*mu;
      double a = (double)gv[c] / sqrt(var + EPS);
      sc_s[tid] = (float)a;
      sh_s[tid] = (float)((double)bv[c] - mu*a);
    }
    __syncthreads();
#pragma unroll
    for (int kpass = 0; kpass < 2; ++kpass){
      int idx = kpass*256 + tid;                 // 0..511
      int px = idx >> 3, co = idx & 7;
      size_t t = (size_t)b*4096 + pt*64 + px;
      uint4 u = *(const uint4*)(Yv + t*256 + ct*64 + co*8);
      const unsigned short* up = (const unsigned short*)&u;
      int c0 = co*8;
#pragma unroll
      for (int e = 0; e < 8; ++e){
        float v = bf2f(up[e]);
        tile[px][c0+e] = f2bf(lrelu(v*sc_s[c0+e] + sh_s[c0+e]));
      }
    }
    __syncthreads();
#pragma unroll
    for (int it = 0; it < 2; ++it){
      int m = it*256 + tid;                      // 512 chunks of 8 keys
      int c2 = m >> 3, kg = m & 7;
      int ch = ct*64 + c2;
      int gc = b*8 + (ch >> 5), l31c = ch & 31;
      int kp = pt*4 + (kg >> 1), l5k = kg & 1;
      unsigned short r0 = tile[kg*8+0][c2], r1 = tile[kg*8+1][c2];
      unsigned short r2 = tile[kg*8+2][c2], r3 = tile[kg*8+3][c2];
      unsigned short r4 = tile[kg*8+4][c2], r5 = tile[kg*8+5][c2];
      unsigned short r6 = tile[kg*8+6][c2], r7 = tile[kg*8+7][c2];
      uint4 u;
      u.x = (unsigned)r0 | ((unsigned)r1<<16);
      u.y = (unsigned)r2 | ((unsigned)r3<<16);
      u.z = (unsigned)r4 | ((unsigned)r5<<16);
      u.w = (unsigned)r6 | ((unsigned)r7<<16);
      *(uint4*)(Vf + ((size_t)((gc*256 + kp)*64 + l5k*32 + l31c))*8) = u;
    }
  }
}

// --------------------------------------------------------------- attention
// R20 state (best measured): R16 structure + R19 swapped-QK^T S-convert;
// P stored FP16. 512 blocks x 512 threads, q-tile 64. blk&7 = (b,half) ->
// XCD-pinned. 8 iters of BK=256, 2 barriers/iter. setprio(1) wraps MFMA.
__global__ __launch_bounds__(512, 4)
void k_attn(const unsigned short* __restrict__ Qf,
            const unsigned short* __restrict__ Kf,
            const unsigned short* __restrict__ Vf,
            __half* __restrict__ P0, __half* __restrict__ P1){
  __shared__ __align__(16) unsigned short Ql[64*256];   // frag-major Q tile
  __shared__ __align__(16) unsigned short Sl[64*264];   // [q][key] padded
  int tid = threadIdx.x;
  int blk = blockIdx.x;
  int qt = blk >> 3, combo = blk & 7;
  int b = combo >> 1, half = combo & 1;
  int q0 = qt*64;
  int lane = tid & 63, w = tid >> 6;
  int l31 = lane & 31, l5 = lane >> 5;
  __half* P = half ? P1 : P0;

  int gq0 = b*128 + qt*2;
  {
    const uint4* src = (const uint4*)(Qf + (size_t)gq0*8192);
    uint4* dst = (uint4*)Ql;
#pragma unroll
    for (int it = 0; it < 4; ++it) dst[it*512 + tid] = src[it*512 + tid];
  }
  __syncthreads();

  f32x16 acc2[2] = {};
  int gk0 = b*128 + half*64 + w;
  const unsigned short* kb = Kf + (size_t)gk0*8192 + lane*8;
  const unsigned short* vb = Vf + ((size_t)((b*8 + w)*256 + half*128))*512 + lane*8;
  const unsigned short* qa0 = Ql + lane*8;
  const unsigned short* qa1 = Ql + 16*512 + lane*8;

  for (int kt = 0; kt < 8; ++kt){
    f32x16 a1[2] = {};
    const unsigned short* kbt = kb + (size_t)kt*8*8192;
    __builtin_amdgcn_s_setprio(1);
#pragma unroll
    for (int ks = 0; ks < 16; ++ks){
      short8 kf = *(const short8*)(kbt + ks*512);
      short8 q0v = *(const short8*)(qa0 + ks*512);
      short8 q1v = *(const short8*)(qa1 + ks*512);
      a1[0] = __builtin_amdgcn_mfma_f32_32x32x16_bf16(kf, q0v, a1[0], 0, 0, 0);
      a1[1] = __builtin_amdgcn_mfma_f32_32x32x16_bf16(kf, q1v, a1[1], 0, 0, 0);
    }
    __builtin_amdgcn_s_setprio(0);
    __syncthreads();     // B0: all waves done reading Sl of iter kt-1
#pragma unroll
    for (int c = 0; c < 2; ++c){
      float t[16];
#pragma unroll
      for (int r = 0; r < 16; ++r){
        float x = a1[c][r];
        t[r] = fmaxf(x, 0.3f*x);
      }
      unsigned p0,p1,p2,p3,p4,p5,p6,p7;
      asm("v_cvt_pk_bf16_f32 %0, %1, %2" : "=v"(p0) : "v"(t[0]),  "v"(t[1]));
      asm("v_cvt_pk_bf16_f32 %0, %1, %2" : "=v"(p1) : "v"(t[2]),  "v"(t[3]));
      asm("v_cvt_pk_bf16_f32 %0, %1, %2" : "=v"(p2) : "v"(t[4]),  "v"(t[5]));
      asm("v_cvt_pk_bf16_f32 %0, %1, %2" : "=v"(p3) : "v"(t[6]),  "v"(t[7]));
      asm("v_cvt_pk_bf16_f32 %0, %1, %2" : "=v"(p4) : "v"(t[8]),  "v"(t[9]));
      asm("v_cvt_pk_bf16_f32 %0, %1, %2" : "=v"(p5) : "v"(t[10]), "v"(t[11]));
      asm("v_cvt_pk_bf16_f32 %0, %1, %2" : "=v"(p6) : "v"(t[12]), "v"(t[13]));
      asm("v_cvt_pk_bf16_f32 %0, %1, %2" : "=v"(p7) : "v"(t[14]), "v"(t[15]));
      asm volatile("v_permlane32_swap_b32 %0, %1" : "+v"(p0), "+v"(p4));
      asm volatile("v_permlane32_swap_b32 %0, %1" : "+v"(p1), "+v"(p5));
      asm volatile("v_permlane32_swap_b32 %0, %1" : "+v"(p2), "+v"(p6));
      asm volatile("v_permlane32_swap_b32 %0, %1" : "+v"(p3), "+v"(p7));
      uint4 u0; u0.x = p0; u0.y = p1; u0.z = p4; u0.w = p5;   // keys +0..7
      uint4 u1; u1.x = p2; u1.y = p3; u1.z = p6; u1.w = p7;   // keys +8..15
      unsigned short* dstp = Sl + (c*32 + l31)*264 + w*32 + l5*16;
      *(uint4*)(dstp)     = u0;
      *(uint4*)(dstp + 8) = u1;
    }
    __syncthreads();     // B1: S visible
    const unsigned short* vbt = vb + (size_t)kt*16*512;
    __builtin_amdgcn_s_setprio(1);
#pragma unroll
    for (int kk = 0; kk < 16; ++kk){
      short8 vf = *(const short8*)(vbt + kk*512);
      short8 s0 = *(const short8*)(Sl + (     l31)*264 + kk*16 + l5*8);
      short8 s1 = *(const short8*)(Sl + (32 + l31)*264 + kk*16 + l5*8);
      acc2[0] = __builtin_amdgcn_mfma_f32_32x32x16_bf16(s0, vf, acc2[0], 0, 0, 0);
      acc2[1] = __builtin_amdgcn_mfma_f32_32x32x16_bf16(s1, vf, acc2[1], 0, 0, 0);
    }
    __builtin_amdgcn_s_setprio(0);
  }
#pragma unroll
  for (int c = 0; c < 2; ++c)
#pragma unroll
    for (int reg = 0; reg < 16; ++reg){
      int row = q0 + c*32 + (reg & 3) + 8*(reg >> 2) + 4*l5;
      P[((size_t)b*4096 + row)*256 + w*32 + l31] = __float2half(acc2[c][reg]);
    }
}

// ------------------------------------------------- partial reduce + BN stats
// 512 blocks x 32 rows. FP16 in/out: thread owns 8 consecutive channels
// (16B/lane); f32 partials -> LDS -> f64 atomics (same accumulation class).
__global__ __launch_bounds__(256)
void k_red(const __half* __restrict__ P0, const __half* __restrict__ P1,
           __half* __restrict__ yout, double* __restrict__ st){
  __shared__ float redS[8][256];
  __shared__ float redQ[8][256];
  int tid = threadIdx.x;
  int cg = (tid & 31)*8, pg = tid >> 5;        // 32 ch-groups x 8 px-groups
  int r0 = blockIdx.x*32;
  float s[8] = {0,0,0,0,0,0,0,0}, q[8] = {0,0,0,0,0,0,0,0};
#pragma unroll
  for (int k = 0; k < 4; ++k){
    size_t idx = (size_t)(r0 + pg + k*8)*256 + cg;
    uint4 ua = *(const uint4*)(P0 + idx);
    uint4 ub = *(const uint4*)(P1 + idx);
    const unsigned short* pa = (const unsigned short*)&ua;
    const unsigned short* pb = (const unsigned short*)&ub;
    unsigned short ho[8];
#pragma unroll
    for (int e = 0; e < 8; ++e){
      float v = h2f(pa[e]) + h2f(pb[e]);
      ho[e] = f2h(v);
      s[e] += v; q[e] += v*v;
    }
    uint4 uo;
    uo.x = (unsigned)ho[0] | ((unsigned)ho[1]<<16);
    uo.y = (unsigned)ho[2] | ((unsigned)ho[3]<<16);
    uo.z = (unsigned)ho[4] | ((unsigned)ho[5]<<16);
    uo.w = (unsigned)ho[6] | ((unsigned)ho[7]<<16);
    *(uint4*)(yout + idx) = uo;
  }
#pragma unroll
  for (int e = 0; e < 8; ++e){
    redS[pg][cg+e] = s[e];
    redQ[pg][cg+e] = q[e];
  }
  __syncthreads();
  float ssum = 0.f, qsum = 0.f;
#pragma unroll
  for (int p = 0; p < 8; ++p){ ssum += redS[p][tid]; qsum += redQ[p][tid]; }
  atomicAdd(&st[1536 + tid], (double)ssum);
  atomicAdd(&st[1792 + tid], (double)qsum);
}

// --------------------------------------------------------------- softmax
// 256 blocks (16,4,4): chunk = 256 rows x 64 ch. FP16 yout, 8 ch/thread.
__global__ __launch_bounds__(256)
void k_soft1(const __half* __restrict__ yout, const double* __restrict__ st,
             const float* __restrict__ g1, float* __restrict__ sums){
  __shared__ float redL[32][64];
  __shared__ float sA[64], sK[64];
  int tid = threadIdx.x;
  int chunk = blockIdx.x, ct = blockIdx.y, b = blockIdx.z;
  int cg = (tid & 7)*8, pg = tid >> 3;         // 8 ch-groups x 32 px-groups
  if (tid < 64){
    int cc = ct*64 + tid;
    double mu  = st[1536 + cc]*(1.0/NTOT);
    double var = st[1792 + cc]*(1.0/NTOT) - mu*mu;
    double a = g1[cc] / sqrt(var + EPS);
    sA[tid] = (float)a;
    sK[tid] = (float)(a*mu);
  }
  __syncthreads();
  float av[8], Kv[8];
#pragma unroll
  for (int e = 0; e < 8; ++e){ av[e] = sA[cg+e]; Kv[e] = sK[cg+e]; }
  const __half* base = yout + ((size_t)b*4096 + chunk*256)*256 + ct*64 + cg;
  float s[8] = {0,0,0,0,0,0,0,0};
#pragma unroll
  for (int k = 0; k < 8; ++k){
    uint4 u = *(const uint4*)(base + (size_t)(pg + k*32)*256);
    const unsigned short* up = (const unsigned short*)&u;
#pragma unroll
    for (int e = 0; e < 8; ++e)
      s[e] += __expf(h2f(up[e])*av[e] - Kv[e]);
  }
#pragma unroll
  for (int e = 0; e < 8; ++e) redL[pg][cg+e] = s[e];
  __syncthreads();
  if (tid < 64){
    float tot = 0.f;
#pragma unroll
    for (int p = 0; p < 32; ++p) tot += redL[p][tid];
    atomicAdd(&sums[b*256 + ct*64 + tid], tot);
  }
}

__global__ __launch_bounds__(256)
void k_soft2(const __half* __restrict__ yout, const double* __restrict__ st,
             const float* __restrict__ g1, const float* __restrict__ sums,
             float* __restrict__ out){
  __shared__ float sA[64], sK[64], sR[64];
  int tid = threadIdx.x;
  int chunk = blockIdx.x, ct = blockIdx.y, b = blockIdx.z;
  int cg = (tid & 7)*8, pg = tid >> 3;
  if (tid < 64){
    int cc = ct*64 + tid;
    double mu  = st[1536 + cc]*(1.0/NTOT);
    double var = st[1792 + cc]*(1.0/NTOT) - mu*mu;
    double a = g1[cc] / sqrt(var + EPS);
    sA[tid] = (float)a;
    sK[tid] = (float)(a*mu);
    sR[tid] = 1.f / sums[b*256 + cc];
  }
  __syncthreads();
  float av[8], Kv[8], rv[8];
#pragma unroll
  for (int e = 0; e < 8; ++e){ av[e] = sA[cg+e]; Kv[e] = sK[cg+e]; rv[e] = sR[cg+e]; }
  const __half* base = yout + ((size_t)b*4096 + chunk*256)*256 + ct*64 + cg;
  float* obase = out + ((size_t)b*4096 + chunk*256)*256 + ct*64 + cg;
#pragma unroll
  for (int k = 0; k < 8; ++k){
    size_t off = (size_t)(pg + k*32)*256;
    uint4 u = *(const uint4*)(base + off);
    const unsigned short* up = (const unsigned short*)&u;
    float o[8];
#pragma unroll
    for (int e = 0; e < 8; ++e)
      o[e] = __expf(h2f(up[e])*av[e] - Kv[e]) * rv[e];
    float4 o0; o0.x = o[0]; o0.y = o[1]; o0.z = o[2]; o0.w = o[3];
    float4 o1; o1.x = o[4]; o1.y = o[5]; o1.z = o[6]; o1.w = o[7];
    *(float4*)(obase + off)     = o0;
    *(float4*)(obase + off + 4) = o1;
  }
}

// ---------------------------------------------------------------------------
extern "C" void kernel_launch(void* const* d_in, const int* in_sizes, int n_in,
                              void* d_out, int out_size, void* d_ws, size_t ws_size,
                              hipStream_t stream){
  (void)in_sizes; (void)n_in; (void)out_size; (void)ws_size;
  const float* X  = (const float*)d_in[0];
  const float* Wq = (const float*)d_in[1];
  const float* gq = (const float*)d_in[2];
  const float* bq = (const float*)d_in[3];
  const float* Wk = (const float*)d_in[4];
  const float* gk = (const float*)d_in[5];
  const float* bk = (const float*)d_in[6];
  const float* Wv = (const float*)d_in[7];
  const float* gv = (const float*)d_in[8];
  const float* bv = (const float*)d_in[9];
  const float* g1 = (const float*)d_in[10];
  // d_in[11] = b1: cancels inside the spatial softmax

  char* ws = (char*)d_ws;
  double*         st   = (double*)ws;                        // 2048 f64 (16KB)
  float*          sums = (float*)(ws + 16384);               // 4KB
  unsigned short* Wt   = (unsigned short*)(ws + 26624);      // 768x256 bf16 -> ends 419840
  unsigned short* Xb   = (unsigned short*)(ws + 419840);     // 8MB -> ends 8808448
  unsigned short* YQK  = (unsigned short*)(ws + 8808448);    // 16MB bf16 frag-major -> 25585664
  unsigned short* Yv   = (unsigned short*)(ws + 25585664);   // 8MB bf16 row-major -> 33974272
  unsigned short* Kf   = (unsigned short*)(ws + 33974272);   // 8MB frag-major -> 42362880
  unsigned short* Vf   = (unsigned short*)(ws + 42362880);   // 8MB frag-major -> 50751488
  __half*         P1   = (__half*)(ws + 50751488);           // 8.4MB (fp16)
  // overlays: Qf on Xb (dead after GEMM); P0 on YQK (dead after bn);
  // yout on Kf+Vf (dead after attn)
  unsigned short* Qf   = Xb;
  __half*         P0   = (__half*)(ws + 8808448);
  __half*         yo   = (__half*)(ws + 33974272);

  k_prep    <<<4145, 256, 0, stream>>>(X, Wq, Wk, Wv, Xb, Wt, (float*)st);
  k_qkv_gemm<<<768, 256, 0, stream>>>(Xb, Wt, YQK, Yv, st);
  k_bn      <<<5120, 256, 0, stream>>>(YQK, Yv, st, gq, bq, gk, bk, gv, bv, Qf, Kf, Vf);
  k_attn    <<<512, 512, 0, stream>>>(Qf, Kf, Vf, P0, P1);
  k_red     <<<512, 256, 0, stream>>>(P0, P1, yo, st);
  k_soft1   <<<dim3(16,4,4), 256, 0, stream>>>(yo, st, g1, sums);
  k_soft2   <<<dim3(16,4,4), 256, 0, stream>>>(yo, st, g1, sums, (float*)d_out);
}